// Round 1
// baseline (1774.814 us; speedup 1.0000x reference)
//
#include <hip/hip_runtime.h>

#define Bn 64
#define Tn 1024
#define Cn 256

// ---------------- DPP helpers (row-scoped lane moves, VALU pipe) ----------------
template<int CTRL>
__device__ __forceinline__ float dpp_mov_f(float x) {
  return __int_as_float(__builtin_amdgcn_update_dpp(0, __float_as_int(x), CTRL, 0xF, 0xF, true));
}
template<int CTRL>
__device__ __forceinline__ int dpp_mov_i(int x) {
  return __builtin_amdgcn_update_dpp(0, x, CTRL, 0xF, 0xF, true);
}

// argmax combine preserving "first occurrence" (lowest index) tie-break,
// matching jnp/np argmax semantics.
__device__ __forceinline__ void combine_argmax(float& v, int& i, float pv, int pi) {
  const bool take = (pv > v) || ((pv == v) && (pi < i));
  v = take ? pv : v;
  i = take ? pi : i;
}

// Full 64-lane argmax (value max, min index on ties). All lanes end with the result.
__device__ __forceinline__ int argmax64(float v, int i, int lane) {
  float pv; int pi;
  pv = dpp_mov_f<0xB1>(v);  pi = dpp_mov_i<0xB1>(i);  combine_argmax(v, i, pv, pi); // xor1 (quad_perm 1,0,3,2)
  pv = dpp_mov_f<0x4E>(v);  pi = dpp_mov_i<0x4E>(i);  combine_argmax(v, i, pv, pi); // xor2 (quad_perm 2,3,0,1)
  pv = dpp_mov_f<0x124>(v); pi = dpp_mov_i<0x124>(i); combine_argmax(v, i, pv, pi); // row_ror:4
  pv = dpp_mov_f<0x128>(v); pi = dpp_mov_i<0x128>(i); combine_argmax(v, i, pv, pi); // row_ror:8 -> full 16-row
  // xor16 within 32-lane halves via ds_swizzle BitMode
  pv = __int_as_float(__builtin_amdgcn_ds_swizzle(__float_as_int(v), 0x401F));
  pi = __builtin_amdgcn_ds_swizzle(i, 0x401F);
  combine_argmax(v, i, pv, pi);
  // xor32 across halves via ds_bpermute (byte index = lane*4)
  const int xaddr = ((lane ^ 32) << 2);
  pv = __int_as_float(__builtin_amdgcn_ds_bpermute(xaddr, __float_as_int(v)));
  pi = __builtin_amdgcn_ds_bpermute(xaddr, i);
  combine_argmax(v, i, pv, pi);
  return i;
}

// ---------------- Kernel A: forward max-plus scan (+ trans transpose) ----------------
// Blocks 0..63  : forward for batch b = blockIdx.x. alpha_t overwrites seq[b][t][:]
//                 (emission t is consumed at step t before being overwritten; the
//                 harness restores d_in before every launch, so mutation is safe).
// Blocks 64..79 : tiled transpose of trans (256x256) into transT (d_ws).
__global__ __launch_bounds__(1024) void crf_fwd_kernel(
    float* __restrict__ seq, const float* __restrict__ trans,
    float* __restrict__ transT, int useT) {
  __shared__ float lds[64 * 65];  // fwd uses first 512 floats as alpha double-buffer
  const int bi = blockIdx.x;
  const int tid = threadIdx.x;

  if (bi < Bn) {
    float* sb = seq + (size_t)bi * (Tn * Cn);
    const int l = tid & 63;
    const int w = tid >> 6;     // wave 0..15
    const int c = l & 15;       // cp-chunk within DPP row
    const int g = l >> 4;       // cc-group within wave (== DPP row id)
    const int ccb = w * 16 + g * 4;  // this thread's 4 consecutive cc
    const int cpb = c * 16;          // this thread's 16 consecutive cp
    // trans fragment: tr4[k] = trans[cpb+k][ccb..ccb+3] (float4, 64 VGPRs)
    float4 tr4[16];
#pragma unroll
    for (int k = 0; k < 16; ++k)
      tr4[k] = *(const float4*)(trans + (size_t)(cpb + k) * Cn + ccb);

    float (*abuf)[Cn] = (float (*)[Cn])lds;
    // alpha_0 = emissions[0] (seq[b][0][:] already holds it; just stage to LDS)
    if (tid < 64) ((float4*)abuf[0])[tid] = ((const float4*)sb)[tid];
    const bool leader = (c == 0);
    float4 e4, pna;
    if (leader) e4 = *(const float4*)(sb + Cn + ccb);  // emissions[1]
    __syncthreads();

    for (int t = 1; t < Tn; ++t) {
      // Early-issue global traffic so the pre-barrier vmcnt drain overlaps compute:
      // store alpha_{t-1} (deferred from last iter), prefetch emissions[t+1].
      float4 pf;
      if (leader) {
        if (t > 1) *(float4*)(sb + (size_t)(t - 1) * Cn + ccb) = pna;
        const int tn = (t + 1 < Tn) ? (t + 1) : (Tn - 1);
        pf = *(const float4*)(sb + (size_t)tn * Cn + ccb);
      }
      const float4* av = (const float4*)abuf[(t - 1) & 1];
      float m0 = -__builtin_inff(), m1 = m0, m2 = m0, m3 = m0;
#pragma unroll
      for (int j = 0; j < 4; ++j) {
        const float4 a = av[c * 4 + j];
        float4 t0 = tr4[4 * j + 0];
        m0 = fmaxf(m0, a.x + t0.x); m1 = fmaxf(m1, a.x + t0.y);
        m2 = fmaxf(m2, a.x + t0.z); m3 = fmaxf(m3, a.x + t0.w);
        float4 t1 = tr4[4 * j + 1];
        m0 = fmaxf(m0, a.y + t1.x); m1 = fmaxf(m1, a.y + t1.y);
        m2 = fmaxf(m2, a.y + t1.z); m3 = fmaxf(m3, a.y + t1.w);
        float4 t2 = tr4[4 * j + 2];
        m0 = fmaxf(m0, a.z + t2.x); m1 = fmaxf(m1, a.z + t2.y);
        m2 = fmaxf(m2, a.z + t2.z); m3 = fmaxf(m3, a.z + t2.w);
        float4 t3 = tr4[4 * j + 3];
        m0 = fmaxf(m0, a.w + t3.x); m1 = fmaxf(m1, a.w + t3.y);
        m2 = fmaxf(m2, a.w + t3.z); m3 = fmaxf(m3, a.w + t3.w);
      }
      // rotate-reduce max across the 16 lanes of this DPP row (exact; max is associative)
      m0 = fmaxf(m0, dpp_mov_f<0x128>(m0)); m1 = fmaxf(m1, dpp_mov_f<0x128>(m1));
      m2 = fmaxf(m2, dpp_mov_f<0x128>(m2)); m3 = fmaxf(m3, dpp_mov_f<0x128>(m3));
      m0 = fmaxf(m0, dpp_mov_f<0x124>(m0)); m1 = fmaxf(m1, dpp_mov_f<0x124>(m1));
      m2 = fmaxf(m2, dpp_mov_f<0x124>(m2)); m3 = fmaxf(m3, dpp_mov_f<0x124>(m3));
      m0 = fmaxf(m0, dpp_mov_f<0x122>(m0)); m1 = fmaxf(m1, dpp_mov_f<0x122>(m1));
      m2 = fmaxf(m2, dpp_mov_f<0x122>(m2)); m3 = fmaxf(m3, dpp_mov_f<0x122>(m3));
      m0 = fmaxf(m0, dpp_mov_f<0x121>(m0)); m1 = fmaxf(m1, dpp_mov_f<0x121>(m1));
      m2 = fmaxf(m2, dpp_mov_f<0x121>(m2)); m3 = fmaxf(m3, dpp_mov_f<0x121>(m3));
      if (leader) {
        float4 na;
        na.x = m0 + e4.x; na.y = m1 + e4.y; na.z = m2 + e4.z; na.w = m3 + e4.w;
        *(float4*)&abuf[t & 1][ccb] = na;  // next step's alpha
        pna = na;                          // deferred global store (next iter top)
        e4 = pf;
      }
      __syncthreads();
    }
    if (leader) *(float4*)(sb + (size_t)(Tn - 1) * Cn + ccb) = pna;
  } else if (useT) {
    // 64x64-tile transpose of trans into transT, LDS-staged, +1-padded (no bank conflicts)
    const int idx = bi - Bn;  // 0..15
    const int ti = idx >> 2, tj = idx & 3;
    const int tx = tid & 63, ty = tid >> 6;  // ty 0..15
#pragma unroll
    for (int q = 0; q < 4; ++q) {
      const int row = q * 16 + ty;
      lds[tx * 65 + row] = trans[(size_t)(ti * 64 + row) * Cn + tj * 64 + tx];
    }
    __syncthreads();
#pragma unroll
    for (int q = 0; q < 4; ++q) {
      const int row = q * 16 + ty;
      transT[(size_t)(tj * 64 + row) * Cn + ti * 64 + tx] = lds[row * 65 + tx];
    }
  }
}

// ---------------- Kernel B: backtrack + one-hot ----------------
// One wave per batch. Recomputes the needed backpointer at each step:
// tag_t = argmax_cp(alpha_t[cp] + trans[cp][tag_{t+1}]) — identical fp32 adds as the
// reference's forward m, hence identical argmax. Writes full one-hot rows (no
// separate zeroing pass needed; d_out is poisoned each launch).
__global__ __launch_bounds__(64) void crf_bwd_kernel(
    const float* __restrict__ seq, const float* __restrict__ trans,
    const float* __restrict__ transT, float* __restrict__ out, int useT) {
  const int b = blockIdx.x;
  const int l = threadIdx.x;
  const int cp0 = l * 4;
  const float* sb = seq + (size_t)b * (Tn * Cn);  // holds alpha_t rows now
  float* ob = out + (size_t)b * (Tn * Cn);

  // last_tag = argmax over alpha_{T-1}
  float4 a = *(const float4*)(sb + (size_t)(Tn - 1) * Cn + cp0);
  float v = a.x; int i = cp0;
  bool cnd;
  cnd = a.y > v; v = cnd ? a.y : v; i = cnd ? cp0 + 1 : i;
  cnd = a.z > v; v = cnd ? a.z : v; i = cnd ? cp0 + 2 : i;
  cnd = a.w > v; v = cnd ? a.w : v; i = cnd ? cp0 + 3 : i;
  int tag = argmax64(v, i, l);
  {
    float4 z;
    z.x = (tag == cp0 + 0) ? 1.0f : 0.0f; z.y = (tag == cp0 + 1) ? 1.0f : 0.0f;
    z.z = (tag == cp0 + 2) ? 1.0f : 0.0f; z.w = (tag == cp0 + 3) ? 1.0f : 0.0f;
    *(float4*)(ob + (size_t)(Tn - 1) * Cn + cp0) = z;
  }

  float4 aN = *(const float4*)(sb + (size_t)(Tn - 2) * Cn + cp0);  // prefetch
  for (int t = Tn - 2; t >= 0; --t) {
    const float4 ac = aN;
    if (t > 0) aN = *(const float4*)(sb + (size_t)(t - 1) * Cn + cp0);  // prefetch next
    float4 tv;
    if (useT) {
      tv = *(const float4*)(transT + (size_t)tag * Cn + cp0);  // coalesced L2-warm row
    } else {
      tv.x = trans[(size_t)(cp0 + 0) * Cn + tag];
      tv.y = trans[(size_t)(cp0 + 1) * Cn + tag];
      tv.z = trans[(size_t)(cp0 + 2) * Cn + tag];
      tv.w = trans[(size_t)(cp0 + 3) * Cn + tag];
    }
    v = ac.x + tv.x; i = cp0;
    float vv;
    vv = ac.y + tv.y; cnd = vv > v; v = cnd ? vv : v; i = cnd ? cp0 + 1 : i;
    vv = ac.z + tv.z; cnd = vv > v; v = cnd ? vv : v; i = cnd ? cp0 + 2 : i;
    vv = ac.w + tv.w; cnd = vv > v; v = cnd ? vv : v; i = cnd ? cp0 + 3 : i;
    tag = argmax64(v, i, l);
    float4 z;
    z.x = (tag == cp0 + 0) ? 1.0f : 0.0f; z.y = (tag == cp0 + 1) ? 1.0f : 0.0f;
    z.z = (tag == cp0 + 2) ? 1.0f : 0.0f; z.w = (tag == cp0 + 3) ? 1.0f : 0.0f;
    *(float4*)(ob + (size_t)t * Cn + cp0) = z;
  }
}

extern "C" void kernel_launch(void* const* d_in, const int* in_sizes, int n_in,
                              void* d_out, int out_size, void* d_ws, size_t ws_size,
                              hipStream_t stream) {
  float* seq = (float*)d_in[0];                    // [B,T,C] fp32 (mutated; restored by harness)
  const float* trans = (const float*)d_in[1];      // [C,C] fp32
  float* out = (float*)d_out;                      // [B,T,C] fp32 one-hot
  float* transT = (float*)d_ws;                    // 256 KB scratch for trans^T
  const int useT = (ws_size >= (size_t)Cn * Cn * sizeof(float)) ? 1 : 0;

  crf_fwd_kernel<<<dim3(Bn + 16), dim3(1024), 0, stream>>>(seq, trans, transT, useT);
  crf_bwd_kernel<<<dim3(Bn), dim3(64), 0, stream>>>(seq, trans, transT, out, useT);
}

// Round 3
// 1630.989 us; speedup vs baseline: 1.0882x; 1.0882x over previous
//
#include <hip/hip_runtime.h>

#define Bn 64
#define Tn 1024
#define Cn 256

// ---------------- DPP helpers (row-scoped lane moves, VALU pipe) ----------------
template<int CTRL>
__device__ __forceinline__ float dpp_mov_f(float x) {
  return __int_as_float(__builtin_amdgcn_update_dpp(0, __float_as_int(x), CTRL, 0xF, 0xF, true));
}

// argmax combine preserving "first occurrence" (lowest index) tie-break,
// matching jnp/np argmax semantics.
__device__ __forceinline__ void combine_argmax(float& v, int& i, float pv, int pi) {
  const bool take = (pv > v) || ((pv == v) && (pi < i));
  v = take ? pv : v;
  i = take ? pi : i;
}

// One DPP reduction stage: pull (v,i) from CTRL-shifted lane; lanes with no
// valid source get old = (-inf, INT_MAX) -> combine is a no-op there.
template<int CTRL>
__device__ __forceinline__ void red_stage(float& v, int& i) {
  const float pv = __int_as_float(__builtin_amdgcn_update_dpp(
      (int)0xFF800000, __float_as_int(v), CTRL, 0xF, 0xF, false));
  const int pi = __builtin_amdgcn_update_dpp(
      0x7FFFFFFF, i, CTRL, 0xF, 0xF, false);
  combine_argmax(v, i, pv, pi);
}

// Full 64-lane argmax (value max, min index on ties), all in the VALU pipe
// (no LDS ops -> no ~120cyc ds latency in the dependent chain).
// row_shr 1/2/4/8 gives lane {15,31,47,63} its 16-lane row result;
// row_bcast15 folds row0->row1 / row2->row3; row_bcast31 folds half0->half1.
// Lane 63 ends with the full 64-lane argmax; broadcast via readlane (SGPR).
__device__ __forceinline__ int argmax64_dpp(float v, int i) {
  red_stage<0x111>(v, i);  // row_shr:1
  red_stage<0x112>(v, i);  // row_shr:2
  red_stage<0x114>(v, i);  // row_shr:4
  red_stage<0x118>(v, i);  // row_shr:8
  red_stage<0x142>(v, i);  // row_bcast15
  red_stage<0x143>(v, i);  // row_bcast31
  return __builtin_amdgcn_readlane(i, 63);
}

// Padded alpha LDS layout: chunk m (float4 #m of the 256-float alpha row) lives
// at float offset (m>>2)*20 + (m&3)*4. Group stride 20 floats => bank-group
// starts {0,20,8,28,16,4,24,12} mod 32 cover all 8 quad-bank groups -> the 16
// distinct ds_read_b128 addresses per step are 2-way max (free, m136), vs the
// old natural layout's 8-way (5.0e7 conflict cycles / dispatch).
__device__ __forceinline__ int apad(int m) { return (m >> 2) * 20 + (m & 3) * 4; }

// ---------------- Kernel A: forward max-plus scan (+ trans transpose) ----------------
// Blocks 0..63  : forward for batch b = blockIdx.x. alpha_t overwrites seq[b][t][:]
//                 (emission t is consumed at step t before being overwritten; the
//                 harness restores d_in before every launch, so mutation is safe).
// Blocks 64..79 : tiled transpose of trans (256x256) into transT (d_ws).
__global__ __launch_bounds__(1024) void crf_fwd_kernel(
    float* __restrict__ seq, const float* __restrict__ trans,
    float* __restrict__ transT, int useT) {
  __shared__ float lds[64 * 65];  // fwd: 2 padded alpha buffers (2*320 floats)
  const int bi = blockIdx.x;
  const int tid = threadIdx.x;

  if (bi < Bn) {
    float* sb = seq + (size_t)bi * (Tn * Cn);
    const int l = tid & 63;
    const int w = tid >> 6;     // wave 0..15
    const int c = l & 15;       // cp-chunk within DPP row
    const int g = l >> 4;       // cc-group within wave (== DPP row id)
    const int ccb = w * 16 + g * 4;  // this thread's 4 consecutive cc
    const int cpb = c * 16;          // this thread's 16 consecutive cp
    // trans fragment: tr4[k] = trans[cpb+k][ccb..ccb+3] (float4, 64 VGPRs)
    float4 tr4[16];
#pragma unroll
    for (int k = 0; k < 16; ++k)
      tr4[k] = *(const float4*)(trans + (size_t)(cpb + k) * Cn + ccb);

    float* ab0 = lds;        // 320 floats (padded)
    float* ab1 = lds + 320;
    // alpha_0 = emissions[0]: stage to LDS in padded layout
    if (tid < 64) *(float4*)(ab0 + apad(tid)) = ((const float4*)sb)[tid];
    const bool leader = (c == 0);
    const int woff = apad(w * 4 + g);  // leader's write slot (chunk w*4+g)
    float4 e4, pna;
    if (leader) e4 = *(const float4*)(sb + Cn + ccb);  // emissions[1]
    __syncthreads();

    for (int t = 1; t < Tn; ++t) {
      // Early-issue global traffic so the pre-barrier vmcnt drain overlaps compute:
      // store alpha_{t-1} (deferred from last iter), prefetch emissions[t+1].
      float4 pf;
      if (leader) {
        if (t > 1) *(float4*)(sb + (size_t)(t - 1) * Cn + ccb) = pna;
        const int tn = (t + 1 < Tn) ? (t + 1) : (Tn - 1);
        pf = *(const float4*)(sb + (size_t)tn * Cn + ccb);
      }
      const float* av = (t & 1) ? ab0 : ab1;  // read buffer for step t
      float* aw = (t & 1) ? ab1 : ab0;        // write buffer (next alpha)
      const float* avc = av + c * 20;         // this lane's 16-cp group (padded)
      float m0 = -__builtin_inff(), m1 = m0, m2 = m0, m3 = m0;
#pragma unroll
      for (int j = 0; j < 4; ++j) {
        const float4 a = *(const float4*)(avc + j * 4);
        float4 t0 = tr4[4 * j + 0];
        m0 = fmaxf(m0, a.x + t0.x); m1 = fmaxf(m1, a.x + t0.y);
        m2 = fmaxf(m2, a.x + t0.z); m3 = fmaxf(m3, a.x + t0.w);
        float4 t1 = tr4[4 * j + 1];
        m0 = fmaxf(m0, a.y + t1.x); m1 = fmaxf(m1, a.y + t1.y);
        m2 = fmaxf(m2, a.y + t1.z); m3 = fmaxf(m3, a.y + t1.w);
        float4 t2 = tr4[4 * j + 2];
        m0 = fmaxf(m0, a.z + t2.x); m1 = fmaxf(m1, a.z + t2.y);
        m2 = fmaxf(m2, a.z + t2.z); m3 = fmaxf(m3, a.z + t2.w);
        float4 t3 = tr4[4 * j + 3];
        m0 = fmaxf(m0, a.w + t3.x); m1 = fmaxf(m1, a.w + t3.y);
        m2 = fmaxf(m2, a.w + t3.z); m3 = fmaxf(m3, a.w + t3.w);
      }
      // rotate-reduce max across the 16 lanes of this DPP row (exact; max is associative)
      m0 = fmaxf(m0, dpp_mov_f<0x128>(m0)); m1 = fmaxf(m1, dpp_mov_f<0x128>(m1));
      m2 = fmaxf(m2, dpp_mov_f<0x128>(m2)); m3 = fmaxf(m3, dpp_mov_f<0x128>(m3));
      m0 = fmaxf(m0, dpp_mov_f<0x124>(m0)); m1 = fmaxf(m1, dpp_mov_f<0x124>(m1));
      m2 = fmaxf(m2, dpp_mov_f<0x124>(m2)); m3 = fmaxf(m3, dpp_mov_f<0x124>(m3));
      m0 = fmaxf(m0, dpp_mov_f<0x122>(m0)); m1 = fmaxf(m1, dpp_mov_f<0x122>(m1));
      m2 = fmaxf(m2, dpp_mov_f<0x122>(m2)); m3 = fmaxf(m3, dpp_mov_f<0x122>(m3));
      m0 = fmaxf(m0, dpp_mov_f<0x121>(m0)); m1 = fmaxf(m1, dpp_mov_f<0x121>(m1));
      m2 = fmaxf(m2, dpp_mov_f<0x121>(m2)); m3 = fmaxf(m3, dpp_mov_f<0x121>(m3));
      if (leader) {
        float4 na;
        na.x = m0 + e4.x; na.y = m1 + e4.y; na.z = m2 + e4.z; na.w = m3 + e4.w;
        *(float4*)(aw + woff) = na;  // next step's alpha (padded slot)
        pna = na;                    // deferred global store (next iter top)
        e4 = pf;
      }
      __syncthreads();
    }
    if (leader) *(float4*)(sb + (size_t)(Tn - 1) * Cn + ccb) = pna;
  } else if (useT) {
    // 64x64-tile transpose of trans into transT, LDS-staged, +1-padded (no bank conflicts)
    const int idx = bi - Bn;  // 0..15
    const int ti = idx >> 2, tj = idx & 3;
    const int tx = tid & 63, ty = tid >> 6;  // ty 0..15
#pragma unroll
    for (int q = 0; q < 4; ++q) {
      const int row = q * 16 + ty;
      lds[tx * 65 + row] = trans[(size_t)(ti * 64 + row) * Cn + tj * 64 + tx];
    }
    __syncthreads();
#pragma unroll
    for (int q = 0; q < 4; ++q) {
      const int row = q * 16 + ty;
      transT[(size_t)(tj * 64 + row) * Cn + ti * 64 + tx] = lds[row * 65 + tx];
    }
  }
}

// ---------------- Kernel B: backtrack + one-hot ----------------
// One wave per batch. Recomputes the needed backpointer at each step:
// tag_t = argmax_cp(alpha_t[cp] + trans[cp][tag_{t+1}]) — identical fp32 adds as the
// reference's forward m, hence identical argmax. Writes full one-hot rows.
// Chain per step: transT row load (L2 ~200cy) -> 4 add/cmp -> 6 DPP stages -> readlane.
// Alpha trail (64MB, HBM ~900cy) prefetched 4 steps ahead:
// invariant at iter t: f0=a[t], f1=a[t-1], f2=a[t-2], f3=a[t-3];
// after shift, refill f3 = a[t-4]  (R2 bug: loaded a[t-5] -> consumed a[t-1] from
// t=T-6 down -> wrong path. Fixed.)
__global__ __launch_bounds__(64) void crf_bwd_kernel(
    const float* __restrict__ seq, const float* __restrict__ trans,
    const float* __restrict__ transT, float* __restrict__ out, int useT) {
  const int b = blockIdx.x;
  const int l = threadIdx.x;
  const int cp0 = l * 4;
  const float* sb = seq + (size_t)b * (Tn * Cn);  // holds alpha_t rows now
  float* ob = out + (size_t)b * (Tn * Cn);

  // last_tag = argmax over alpha_{T-1}
  float4 a = *(const float4*)(sb + (size_t)(Tn - 1) * Cn + cp0);
  float v = a.x; int i = cp0;
  bool cnd;
  cnd = a.y > v; v = cnd ? a.y : v; i = cnd ? cp0 + 1 : i;
  cnd = a.z > v; v = cnd ? a.z : v; i = cnd ? cp0 + 2 : i;
  cnd = a.w > v; v = cnd ? a.w : v; i = cnd ? cp0 + 3 : i;
  int tag = argmax64_dpp(v, i);
  {
    float4 z;
    z.x = (tag == cp0 + 0) ? 1.0f : 0.0f; z.y = (tag == cp0 + 1) ? 1.0f : 0.0f;
    z.z = (tag == cp0 + 2) ? 1.0f : 0.0f; z.w = (tag == cp0 + 3) ? 1.0f : 0.0f;
    *(float4*)(ob + (size_t)(Tn - 1) * Cn + cp0) = z;
  }

  // Rolling 4-deep alpha prefetch queue (covers ~900cy HBM miss at ~350cy/step).
  float4 f0 = *(const float4*)(sb + (size_t)(Tn - 2) * Cn + cp0);
  float4 f1 = *(const float4*)(sb + (size_t)(Tn - 3) * Cn + cp0);
  float4 f2 = *(const float4*)(sb + (size_t)(Tn - 4) * Cn + cp0);
  float4 f3 = *(const float4*)(sb + (size_t)(Tn - 5) * Cn + cp0);
#pragma unroll 4
  for (int t = Tn - 2; t >= 0; --t) {
    const float4 ac = f0;
    f0 = f1; f1 = f2; f2 = f3;
    const int tp = (t >= 4) ? (t - 4) : 0;  // refill: a[t-4] keeps the invariant
    f3 = *(const float4*)(sb + (size_t)tp * Cn + cp0);
    float4 tv;
    if (useT) {
      tv = *(const float4*)(transT + (size_t)tag * Cn + cp0);  // coalesced, SGPR tag
    } else {
      tv.x = trans[(size_t)(cp0 + 0) * Cn + tag];
      tv.y = trans[(size_t)(cp0 + 1) * Cn + tag];
      tv.z = trans[(size_t)(cp0 + 2) * Cn + tag];
      tv.w = trans[(size_t)(cp0 + 3) * Cn + tag];
    }
    v = ac.x + tv.x; i = cp0;
    float vv;
    vv = ac.y + tv.y; cnd = vv > v; v = cnd ? vv : v; i = cnd ? cp0 + 1 : i;
    vv = ac.z + tv.z; cnd = vv > v; v = cnd ? vv : v; i = cnd ? cp0 + 2 : i;
    vv = ac.w + tv.w; cnd = vv > v; v = cnd ? vv : v; i = cnd ? cp0 + 3 : i;
    tag = argmax64_dpp(v, i);
    float4 z;
    z.x = (tag == cp0 + 0) ? 1.0f : 0.0f; z.y = (tag == cp0 + 1) ? 1.0f : 0.0f;
    z.z = (tag == cp0 + 2) ? 1.0f : 0.0f; z.w = (tag == cp0 + 3) ? 1.0f : 0.0f;
    *(float4*)(ob + (size_t)t * Cn + cp0) = z;
  }
}

extern "C" void kernel_launch(void* const* d_in, const int* in_sizes, int n_in,
                              void* d_out, int out_size, void* d_ws, size_t ws_size,
                              hipStream_t stream) {
  float* seq = (float*)d_in[0];                    // [B,T,C] fp32 (mutated; restored by harness)
  const float* trans = (const float*)d_in[1];      // [C,C] fp32
  float* out = (float*)d_out;                      // [B,T,C] fp32 one-hot
  float* transT = (float*)d_ws;                    // 256 KB scratch for trans^T
  const int useT = (ws_size >= (size_t)Cn * Cn * sizeof(float)) ? 1 : 0;

  crf_fwd_kernel<<<dim3(Bn + 16), dim3(1024), 0, stream>>>(seq, trans, transT, useT);
  crf_bwd_kernel<<<dim3(Bn), dim3(64), 0, stream>>>(seq, trans, transT, out, useT);
}

// Round 4
// 1538.059 us; speedup vs baseline: 1.1539x; 1.0604x over previous
//
#include <hip/hip_runtime.h>

#define Bn 64
#define Tn 1024
#define Cn 256

// ---------------- DPP helpers (row-scoped lane moves, VALU pipe) ----------------
template<int CTRL>
__device__ __forceinline__ float dpp_mov_f(float x) {
  return __int_as_float(__builtin_amdgcn_update_dpp(0, __float_as_int(x), CTRL, 0xF, 0xF, true));
}

// argmax combine preserving "first occurrence" (lowest index) tie-break,
// matching jnp/np argmax semantics.
__device__ __forceinline__ void combine_argmax(float& v, int& i, float pv, int pi) {
  const bool take = (pv > v) || ((pv == v) && (pi < i));
  v = take ? pv : v;
  i = take ? pi : i;
}

// One DPP reduction stage: pull (v,i) from CTRL-shifted lane; lanes with no
// valid source get old = (-inf, INT_MAX) -> combine is a no-op there.
template<int CTRL>
__device__ __forceinline__ void red_stage(float& v, int& i) {
  const float pv = __int_as_float(__builtin_amdgcn_update_dpp(
      (int)0xFF800000, __float_as_int(v), CTRL, 0xF, 0xF, false));
  const int pi = __builtin_amdgcn_update_dpp(
      0x7FFFFFFF, i, CTRL, 0xF, 0xF, false);
  combine_argmax(v, i, pv, pi);
}

// Full 64-lane argmax (value max, min index on ties), all in the VALU pipe.
__device__ __forceinline__ int argmax64_dpp(float v, int i) {
  red_stage<0x111>(v, i);  // row_shr:1
  red_stage<0x112>(v, i);  // row_shr:2
  red_stage<0x114>(v, i);  // row_shr:4
  red_stage<0x118>(v, i);  // row_shr:8
  red_stage<0x142>(v, i);  // row_bcast15
  red_stage<0x143>(v, i);  // row_bcast31
  return __builtin_amdgcn_readlane(i, 63);
}

// Padded alpha LDS layout: chunk m at float offset (m>>2)*20 + (m&3)*4.
// Verified R3: SQ_LDS_BANK_CONFLICT 5.0e7 -> 512.
__device__ __forceinline__ int apad(int m) { return (m >> 2) * 20 + (m & 3) * 4; }

// ---------------- Kernel A: forward max-plus scan (+ trans transpose) ----------------
__global__ __launch_bounds__(1024) void crf_fwd_kernel(
    float* __restrict__ seq, const float* __restrict__ trans,
    float* __restrict__ transT, int useT) {
  __shared__ float lds[64 * 65];
  const int bi = blockIdx.x;
  const int tid = threadIdx.x;

  if (bi < Bn) {
    float* sb = seq + (size_t)bi * (Tn * Cn);
    const int l = tid & 63;
    const int w = tid >> 6;     // wave 0..15
    const int c = l & 15;       // cp-chunk within DPP row
    const int g = l >> 4;       // cc-group within wave
    const int ccb = w * 16 + g * 4;
    const int cpb = c * 16;
    float4 tr4[16];
#pragma unroll
    for (int k = 0; k < 16; ++k)
      tr4[k] = *(const float4*)(trans + (size_t)(cpb + k) * Cn + ccb);

    float* ab0 = lds;        // 320 floats (padded)
    float* ab1 = lds + 320;
    if (tid < 64) *(float4*)(ab0 + apad(tid)) = ((const float4*)sb)[tid];
    const bool leader = (c == 0);
    const int woff = apad(w * 4 + g);
    // Emission queue depth 2: at step t, e0 = emissions[t]; prefetch t+2 so the
    // pre-barrier vmcnt(0) drain never waits on an in-flight HBM load.
    float4 e0, e1, pna;
    if (leader) {
      e0 = *(const float4*)(sb + (size_t)1 * Cn + ccb);
      e1 = *(const float4*)(sb + (size_t)2 * Cn + ccb);
    }
    __syncthreads();

    for (int t = 1; t < Tn; ++t) {
      float4 pf;
      if (leader) {
        if (t > 1) *(float4*)(sb + (size_t)(t - 1) * Cn + ccb) = pna;
        const int tn = (t + 2 < Tn) ? (t + 2) : (Tn - 1);
        pf = *(const float4*)(sb + (size_t)tn * Cn + ccb);
      }
      const float* av = (t & 1) ? ab0 : ab1;
      float* aw = (t & 1) ? ab1 : ab0;
      const float* avc = av + c * 20;
      float m0 = -__builtin_inff(), m1 = m0, m2 = m0, m3 = m0;
#pragma unroll
      for (int j = 0; j < 4; ++j) {
        const float4 a = *(const float4*)(avc + j * 4);
        float4 t0 = tr4[4 * j + 0];
        m0 = fmaxf(m0, a.x + t0.x); m1 = fmaxf(m1, a.x + t0.y);
        m2 = fmaxf(m2, a.x + t0.z); m3 = fmaxf(m3, a.x + t0.w);
        float4 t1 = tr4[4 * j + 1];
        m0 = fmaxf(m0, a.y + t1.x); m1 = fmaxf(m1, a.y + t1.y);
        m2 = fmaxf(m2, a.y + t1.z); m3 = fmaxf(m3, a.y + t1.w);
        float4 t2 = tr4[4 * j + 2];
        m0 = fmaxf(m0, a.z + t2.x); m1 = fmaxf(m1, a.z + t2.y);
        m2 = fmaxf(m2, a.z + t2.z); m3 = fmaxf(m3, a.z + t2.w);
        float4 t3 = tr4[4 * j + 3];
        m0 = fmaxf(m0, a.w + t3.x); m1 = fmaxf(m1, a.w + t3.y);
        m2 = fmaxf(m2, a.w + t3.z); m3 = fmaxf(m3, a.w + t3.w);
      }
      // rotate-reduce max across the 16 lanes of this DPP row (exact)
      m0 = fmaxf(m0, dpp_mov_f<0x128>(m0)); m1 = fmaxf(m1, dpp_mov_f<0x128>(m1));
      m2 = fmaxf(m2, dpp_mov_f<0x128>(m2)); m3 = fmaxf(m3, dpp_mov_f<0x128>(m3));
      m0 = fmaxf(m0, dpp_mov_f<0x124>(m0)); m1 = fmaxf(m1, dpp_mov_f<0x124>(m1));
      m2 = fmaxf(m2, dpp_mov_f<0x124>(m2)); m3 = fmaxf(m3, dpp_mov_f<0x124>(m3));
      m0 = fmaxf(m0, dpp_mov_f<0x122>(m0)); m1 = fmaxf(m1, dpp_mov_f<0x122>(m1));
      m2 = fmaxf(m2, dpp_mov_f<0x122>(m2)); m3 = fmaxf(m3, dpp_mov_f<0x122>(m3));
      m0 = fmaxf(m0, dpp_mov_f<0x121>(m0)); m1 = fmaxf(m1, dpp_mov_f<0x121>(m1));
      m2 = fmaxf(m2, dpp_mov_f<0x121>(m2)); m3 = fmaxf(m3, dpp_mov_f<0x121>(m3));
      if (leader) {
        float4 na;
        na.x = m0 + e0.x; na.y = m1 + e0.y; na.z = m2 + e0.z; na.w = m3 + e0.w;
        *(float4*)(aw + woff) = na;
        pna = na;
        e0 = e1; e1 = pf;
      }
      __syncthreads();
    }
    if (leader) *(float4*)(sb + (size_t)(Tn - 1) * Cn + ccb) = pna;
  } else if (useT) {
    const int idx = bi - Bn;  // 0..15
    const int ti = idx >> 2, tj = idx & 3;
    const int tx = tid & 63, ty = tid >> 6;
#pragma unroll
    for (int q = 0; q < 4; ++q) {
      const int row = q * 16 + ty;
      lds[tx * 65 + row] = trans[(size_t)(ti * 64 + row) * Cn + tj * 64 + tx];
    }
    __syncthreads();
#pragma unroll
    for (int q = 0; q < 4; ++q) {
      const int row = q * 16 + ty;
      transT[(size_t)(tj * 64 + row) * Cn + ti * 64 + tx] = lds[row * 65 + tx];
    }
  }
}

// ---------------- Kernel B: chunked backtrack + one-hot ----------------
// R3 bwd was 1642 cy/step: the rolling prefetch put an HBM alpha load in the
// vmcnt queue every iteration; vmcnt retires IN ORDER, so waiting for the
// newest (transT) load = vmcnt(0) = drain the ~900cy HBM prefetch each step.
// Fix: 16-step chunks with separated phases:
//   P: burst-load 16 alpha rows -> registers   (16 vmem loads)
//   C: pure dependent chain; per step the ONLY vmem op is transT[tag] (L2).
//      First wait absorbs the P burst once per chunk (~900cy/16 steps).
//   S: burst-store 16 one-hot rows.
// sched_barrier(0) pins the phase boundaries.
template<int N>
__device__ __forceinline__ int chunk_steps(
    const float* __restrict__ sb, const float* __restrict__ transT,
    float* __restrict__ ob, int t0, int tag, int cp0) {
  float4 f[N];
#pragma unroll
  for (int k = 0; k < N; ++k)
    f[k] = *(const float4*)(sb + (size_t)(t0 - k) * Cn + cp0);
  __builtin_amdgcn_sched_barrier(0);
  int tags[N];
#pragma unroll
  for (int k = 0; k < N; ++k) {
    const float4 tv = *(const float4*)(transT + (size_t)tag * Cn + cp0);
    const float4 ac = f[k];
    float v = ac.x + tv.x; int i = cp0;
    float vv; bool cnd;
    vv = ac.y + tv.y; cnd = vv > v; v = cnd ? vv : v; i = cnd ? cp0 + 1 : i;
    vv = ac.z + tv.z; cnd = vv > v; v = cnd ? vv : v; i = cnd ? cp0 + 2 : i;
    vv = ac.w + tv.w; cnd = vv > v; v = cnd ? vv : v; i = cnd ? cp0 + 3 : i;
    tag = argmax64_dpp(v, i);
    tags[k] = tag;
  }
  __builtin_amdgcn_sched_barrier(0);
#pragma unroll
  for (int k = 0; k < N; ++k) {
    const int tg = tags[k];
    float4 z;
    z.x = (tg == cp0 + 0) ? 1.0f : 0.0f; z.y = (tg == cp0 + 1) ? 1.0f : 0.0f;
    z.z = (tg == cp0 + 2) ? 1.0f : 0.0f; z.w = (tg == cp0 + 3) ? 1.0f : 0.0f;
    *(float4*)(ob + (size_t)(t0 - k) * Cn + cp0) = z;
  }
  return tag;
}

__global__ __launch_bounds__(64) void crf_bwd_kernel(
    const float* __restrict__ seq, const float* __restrict__ trans,
    const float* __restrict__ transT, float* __restrict__ out, int useT) {
  const int b = blockIdx.x;
  const int l = threadIdx.x;
  const int cp0 = l * 4;
  const float* sb = seq + (size_t)b * (Tn * Cn);  // holds alpha_t rows now
  float* ob = out + (size_t)b * (Tn * Cn);

  // last_tag = argmax over alpha_{T-1}
  float4 a = *(const float4*)(sb + (size_t)(Tn - 1) * Cn + cp0);
  float v = a.x; int i = cp0;
  bool cnd;
  cnd = a.y > v; v = cnd ? a.y : v; i = cnd ? cp0 + 1 : i;
  cnd = a.z > v; v = cnd ? a.z : v; i = cnd ? cp0 + 2 : i;
  cnd = a.w > v; v = cnd ? a.w : v; i = cnd ? cp0 + 3 : i;
  int tag = argmax64_dpp(v, i);
  {
    float4 z;
    z.x = (tag == cp0 + 0) ? 1.0f : 0.0f; z.y = (tag == cp0 + 1) ? 1.0f : 0.0f;
    z.z = (tag == cp0 + 2) ? 1.0f : 0.0f; z.w = (tag == cp0 + 3) ? 1.0f : 0.0f;
    *(float4*)(ob + (size_t)(Tn - 1) * Cn + cp0) = z;
  }

  if (useT) {
    // 1023 steps: first chunk of 15 (t=1022..1008), then 63 chunks of 16 (t=1007..0)
    tag = chunk_steps<15>(sb, transT, ob, Tn - 2, tag, cp0);
    for (int ch = 0; ch < 63; ++ch)
      tag = chunk_steps<16>(sb, transT, ob, 1007 - ch * 16, tag, cp0);
  } else {
    // Fallback (no workspace): simple correct loop, strided trans reads.
    for (int t = Tn - 2; t >= 0; --t) {
      const float4 ac = *(const float4*)(sb + (size_t)t * Cn + cp0);
      float4 tv;
      tv.x = trans[(size_t)(cp0 + 0) * Cn + tag];
      tv.y = trans[(size_t)(cp0 + 1) * Cn + tag];
      tv.z = trans[(size_t)(cp0 + 2) * Cn + tag];
      tv.w = trans[(size_t)(cp0 + 3) * Cn + tag];
      v = ac.x + tv.x; i = cp0;
      float vv;
      vv = ac.y + tv.y; cnd = vv > v; v = cnd ? vv : v; i = cnd ? cp0 + 1 : i;
      vv = ac.z + tv.z; cnd = vv > v; v = cnd ? vv : v; i = cnd ? cp0 + 2 : i;
      vv = ac.w + tv.w; cnd = vv > v; v = cnd ? vv : v; i = cnd ? cp0 + 3 : i;
      tag = argmax64_dpp(v, i);
      float4 z;
      z.x = (tag == cp0 + 0) ? 1.0f : 0.0f; z.y = (tag == cp0 + 1) ? 1.0f : 0.0f;
      z.z = (tag == cp0 + 2) ? 1.0f : 0.0f; z.w = (tag == cp0 + 3) ? 1.0f : 0.0f;
      *(float4*)(ob + (size_t)t * Cn + cp0) = z;
    }
  }
}

extern "C" void kernel_launch(void* const* d_in, const int* in_sizes, int n_in,
                              void* d_out, int out_size, void* d_ws, size_t ws_size,
                              hipStream_t stream) {
  float* seq = (float*)d_in[0];
  const float* trans = (const float*)d_in[1];
  float* out = (float*)d_out;
  float* transT = (float*)d_ws;
  const int useT = (ws_size >= (size_t)Cn * Cn * sizeof(float)) ? 1 : 0;

  crf_fwd_kernel<<<dim3(Bn + 16), dim3(1024), 0, stream>>>(seq, trans, transT, useT);
  crf_bwd_kernel<<<dim3(Bn), dim3(64), 0, stream>>>(seq, trans, transT, out, useT);
}

// Round 5
// 1448.899 us; speedup vs baseline: 1.2249x; 1.0615x over previous
//
#include <hip/hip_runtime.h>

#define Bn 64
#define Tn 1024
#define Cn 256

// ---------------- DPP helpers ----------------
template<int CTRL>
__device__ __forceinline__ float dpp_mov_f(float x) {
  return __int_as_float(__builtin_amdgcn_update_dpp(0, __float_as_int(x), CTRL, 0xF, 0xF, true));
}
// value-only max stage: pull from CTRL-shifted lane, -inf fill for invalid sources
template<int CTRL>
__device__ __forceinline__ void max_stage(float& v) {
  const float pv = __int_as_float(__builtin_amdgcn_update_dpp(
      (int)0xFF800000, __float_as_int(v), CTRL, 0xF, 0xF, false));
  v = fmaxf(v, pv);
}

// Fast 64-lane argmax (min index on ties), short dependent chain:
// 6 dpp fmax (value only) -> readlane(max) -> ballot(v==max) -> ff1 -> readlane(i).
// Tie-break: first set lane = lowest lane = lowest cp block; each thread's local i
// is already the first index within its 4 -> global first index. Matches jnp argmax.
__device__ __forceinline__ int argmax64_fast(float v, int i) {
  float mv = v;
  max_stage<0x111>(mv);  // row_shr:1
  max_stage<0x112>(mv);  // row_shr:2
  max_stage<0x114>(mv);  // row_shr:4
  max_stage<0x118>(mv);  // row_shr:8
  max_stage<0x142>(mv);  // row_bcast15
  max_stage<0x143>(mv);  // row_bcast31  -> lane 63 has global max
  const float smax = __int_as_float(__builtin_amdgcn_readlane(__float_as_int(mv), 63));
  const unsigned long long m = __ballot(v == smax);
  const int ln = __ffsll((unsigned long long)m) - 1;
  return __builtin_amdgcn_readlane(i, ln);
}

// Padded alpha LDS layout (verified R3: SQ_LDS_BANK_CONFLICT 5.0e7 -> 512):
// chunk m at float offset (m>>2)*20 + (m&3)*4.
__device__ __forceinline__ int apad(int m) { return (m >> 2) * 20 + (m & 3) * 4; }

// ---------------- fwd chunk: K steps, PK deferred alpha stores ----------------
// Leaders burst-store previous chunk's alphas + burst-load this chunk's emissions
// at chunk top; inner steps touch only LDS -> K-1 of K barriers drain nothing
// (the __syncthreads vmcnt(0) drain is the structural cost found in R4).
template<int K, int PK>
__device__ __forceinline__ void fwd_chunk(
    int tb, float* __restrict__ sb, int ccb, bool leader, int c,
    float* ab0, float* ab1, int woff0, int woff1, const float4* tr4,
    float4 (&e)[4][2], float4 (&na)[4][2]) {
  if (leader) {
#pragma unroll
    for (int k = 0; k < PK; ++k) {
      *(float4*)(sb + (size_t)(tb - PK + k) * Cn + ccb) = na[k][0];
      *(float4*)(sb + (size_t)(tb - PK + k) * Cn + ccb + 4) = na[k][1];
    }
#pragma unroll
    for (int k = 0; k < K; ++k) {
      e[k][0] = *(const float4*)(sb + (size_t)(tb + k) * Cn + ccb);
      e[k][1] = *(const float4*)(sb + (size_t)(tb + k) * Cn + ccb + 4);
    }
  }
#pragma unroll
  for (int k = 0; k < K; ++k) {
    const int t = tb + k;
    const float* av = (t & 1) ? ab0 : ab1;
    float* aw = (t & 1) ? ab1 : ab0;
    const float* avc = av + c * 20;
    float m0 = -__builtin_inff(), m1 = m0, m2 = m0, m3 = m0,
          m4 = m0, m5 = m0, m6 = m0, m7 = m0;
#pragma unroll
    for (int j = 0; j < 4; ++j) {
      const float4 a = *(const float4*)(avc + 4 * j);
#define STEP8(av_, kk)                                                            \
      {                                                                           \
        const float4 tA = tr4[(kk) * 2 + 0];                                      \
        const float4 tB = tr4[(kk) * 2 + 1];                                      \
        m0 = fmaxf(m0, (av_) + tA.x); m1 = fmaxf(m1, (av_) + tA.y);               \
        m2 = fmaxf(m2, (av_) + tA.z); m3 = fmaxf(m3, (av_) + tA.w);               \
        m4 = fmaxf(m4, (av_) + tB.x); m5 = fmaxf(m5, (av_) + tB.y);               \
        m6 = fmaxf(m6, (av_) + tB.z); m7 = fmaxf(m7, (av_) + tB.w);               \
      }
      STEP8(a.x, 4 * j + 0)
      STEP8(a.y, 4 * j + 1)
      STEP8(a.z, 4 * j + 2)
      STEP8(a.w, 4 * j + 3)
#undef STEP8
    }
    // rotate-reduce max across the 16 c-lanes of this DPP row (exact)
#define ROR8(CTRL)                                                                \
    m0 = fmaxf(m0, dpp_mov_f<CTRL>(m0)); m1 = fmaxf(m1, dpp_mov_f<CTRL>(m1));     \
    m2 = fmaxf(m2, dpp_mov_f<CTRL>(m2)); m3 = fmaxf(m3, dpp_mov_f<CTRL>(m3));     \
    m4 = fmaxf(m4, dpp_mov_f<CTRL>(m4)); m5 = fmaxf(m5, dpp_mov_f<CTRL>(m5));     \
    m6 = fmaxf(m6, dpp_mov_f<CTRL>(m6)); m7 = fmaxf(m7, dpp_mov_f<CTRL>(m7));
    ROR8(0x128) ROR8(0x124) ROR8(0x122) ROR8(0x121)
#undef ROR8
    if (leader) {
      float4 n0, n1;
      n0.x = m0 + e[k][0].x; n0.y = m1 + e[k][0].y;
      n0.z = m2 + e[k][0].z; n0.w = m3 + e[k][0].w;
      n1.x = m4 + e[k][1].x; n1.y = m5 + e[k][1].y;
      n1.z = m6 + e[k][1].z; n1.w = m7 + e[k][1].w;
      *(float4*)(aw + woff0) = n0;
      *(float4*)(aw + woff1) = n1;
      na[k][0] = n0; na[k][1] = n1;
    }
    __syncthreads();
  }
}

// ---------------- Kernel A: forward (8 waves; halves LDS redundancy vs 16) -----
// Blocks 0..63: forward for batch b. alpha_t overwrites seq[b][t][:] (harness
// restores inputs each launch). Blocks 64..79: transpose trans -> transT (d_ws).
__global__ __launch_bounds__(512, 2) void crf_fwd_kernel(
    float* __restrict__ seq, const float* __restrict__ trans,
    float* __restrict__ transT, int useT) {
  __shared__ float lds[64 * 65];
  const int bi = blockIdx.x;
  const int tid = threadIdx.x;

  if (bi < Bn) {
    float* sb = seq + (size_t)bi * (Tn * Cn);
    const int l = tid & 63;
    const int w = tid >> 6;          // wave 0..7
    const int c = l & 15;            // cp-chunk lane (reduction index)
    const int g = l >> 4;            // 0..3
    const int ccb = w * 32 + g * 8;  // this thread's 8 consecutive cc
    const int cpb = c * 16;          // this thread's 16 consecutive cp
    float4 tr4[32];                  // trans[cpb+k][ccb..ccb+7], k=0..15 (128 VGPR)
#pragma unroll
    for (int k = 0; k < 16; ++k) {
      tr4[2 * k + 0] = *(const float4*)(trans + (size_t)(cpb + k) * Cn + ccb);
      tr4[2 * k + 1] = *(const float4*)(trans + (size_t)(cpb + k) * Cn + ccb + 4);
    }
    float* ab0 = lds;
    float* ab1 = lds + 320;
    if (tid < 64) *(float4*)(ab0 + apad(tid)) = ((const float4*)sb)[tid];
    const bool leader = (c == 0);
    const int m0c = w * 8 + g * 2;   // leader's two alpha chunks
    const int woff0 = apad(m0c), woff1 = apad(m0c + 1);
    float4 e[4][2], na[4][2];
    __syncthreads();

    fwd_chunk<3, 0>(1, sb, ccb, leader, c, ab0, ab1, woff0, woff1, tr4, e, na);
    fwd_chunk<4, 3>(4, sb, ccb, leader, c, ab0, ab1, woff0, woff1, tr4, e, na);
    for (int tb = 8; tb < Tn; tb += 4)
      fwd_chunk<4, 4>(tb, sb, ccb, leader, c, ab0, ab1, woff0, woff1, tr4, e, na);
    if (leader) {
#pragma unroll
      for (int k = 0; k < 4; ++k) {
        *(float4*)(sb + (size_t)(1020 + k) * Cn + ccb) = na[k][0];
        *(float4*)(sb + (size_t)(1020 + k) * Cn + ccb + 4) = na[k][1];
      }
    }
  } else if (useT) {
    // 64x64-tile transpose, LDS-staged, +1-padded
    const int idx = bi - Bn;  // 0..15
    const int ti = idx >> 2, tj = idx & 3;
    const int tx = tid & 63, ty = tid >> 6;  // ty 0..7
#pragma unroll
    for (int q = 0; q < 8; ++q) {
      const int row = q * 8 + ty;
      lds[tx * 65 + row] = trans[(size_t)(ti * 64 + row) * Cn + tj * 64 + tx];
    }
    __syncthreads();
#pragma unroll
    for (int q = 0; q < 8; ++q) {
      const int row = q * 8 + ty;
      transT[(size_t)(tj * 64 + row) * Cn + ti * 64 + tx] = lds[row * 65 + tx];
    }
  }
}

// ---------------- bwd chain chunk (wave 0 only) ----------------
__device__ __forceinline__ float4 onehot4(int tg, int cp0) {
  float4 z;
  z.x = (tg == cp0 + 0) ? 1.0f : 0.0f; z.y = (tg == cp0 + 1) ? 1.0f : 0.0f;
  z.z = (tg == cp0 + 2) ? 1.0f : 0.0f; z.w = (tg == cp0 + 3) ? 1.0f : 0.0f;
  return z;
}

template<int K>
__device__ __forceinline__ int chain_chunk(
    const float* __restrict__ A, int* __restrict__ tags,
    const float* __restrict__ transT, int tag, int l) {
  const int cp0 = l * 4;
#pragma unroll
  for (int k = 0; k < K; ++k) {
    const float4 tv = *(const float4*)(transT + (size_t)tag * Cn + cp0);
    const float4 ac = *(const float4*)(A + k * Cn + cp0);
    float v = ac.x + tv.x; int i = cp0;
    float vv; bool cnd;
    vv = ac.y + tv.y; cnd = vv > v; v = cnd ? vv : v; i = cnd ? cp0 + 1 : i;
    vv = ac.z + tv.z; cnd = vv > v; v = cnd ? vv : v; i = cnd ? cp0 + 2 : i;
    vv = ac.w + tv.w; cnd = vv > v; v = cnd ? vv : v; i = cnd ? cp0 + 3 : i;
    tag = argmax64_fast(v, i);
    if (l == 0) tags[k] = tag;
  }
  return tag;
}

// ---------------- Kernel B: producer-consumer backtrack + one-hot -------------
// 4 waves/block. Wave0: pure dependent chain (only vmem op = transT[tag], L2).
// Waves1-2: prefetch next chunk's 16 alpha rows global->LDS ring.
// Wave3: store previous chunk's one-hot rows from tags in LDS.
// Barrier once per 16 steps; each wave drains only its OWN counters -> the
// ~900cy HBM alpha loads never sit in the chain wave's vmcnt queue (R4 lesson).
__global__ __launch_bounds__(256) void crf_bwd_kernel(
    const float* __restrict__ seq, const float* __restrict__ trans,
    const float* __restrict__ transT, float* __restrict__ out, int useT) {
  __shared__ float aL[2][16][Cn];   // 32 KB alpha ring
  __shared__ int tagL[2][16];
  const int b = blockIdx.x;
  const int tid = threadIdx.x;
  const int wv = tid >> 6;
  const int l = tid & 63;
  const int cp0 = l * 4;
  const float* sb = seq + (size_t)b * (Tn * Cn);  // alpha trail
  float* ob = out + (size_t)b * (Tn * Cn);

  if (!useT) {
    // Fallback: single-wave simple loop (ws too small for transT).
    if (wv == 0) {
      float4 a = *(const float4*)(sb + (size_t)(Tn - 1) * Cn + cp0);
      float v = a.x; int i = cp0; bool cnd;
      cnd = a.y > v; v = cnd ? a.y : v; i = cnd ? cp0 + 1 : i;
      cnd = a.z > v; v = cnd ? a.z : v; i = cnd ? cp0 + 2 : i;
      cnd = a.w > v; v = cnd ? a.w : v; i = cnd ? cp0 + 3 : i;
      int tag = argmax64_fast(v, i);
      *(float4*)(ob + (size_t)(Tn - 1) * Cn + cp0) = onehot4(tag, cp0);
      for (int t = Tn - 2; t >= 0; --t) {
        const float4 ac = *(const float4*)(sb + (size_t)t * Cn + cp0);
        float4 tv;
        tv.x = trans[(size_t)(cp0 + 0) * Cn + tag];
        tv.y = trans[(size_t)(cp0 + 1) * Cn + tag];
        tv.z = trans[(size_t)(cp0 + 2) * Cn + tag];
        tv.w = trans[(size_t)(cp0 + 3) * Cn + tag];
        float v2 = ac.x + tv.x; int i2 = cp0; float vv; bool c2;
        vv = ac.y + tv.y; c2 = vv > v2; v2 = c2 ? vv : v2; i2 = c2 ? cp0 + 1 : i2;
        vv = ac.z + tv.z; c2 = vv > v2; v2 = c2 ? vv : v2; i2 = c2 ? cp0 + 2 : i2;
        vv = ac.w + tv.w; c2 = vv > v2; v2 = c2 ? vv : v2; i2 = c2 ? cp0 + 3 : i2;
        tag = argmax64_fast(v2, i2);
        *(float4*)(ob + (size_t)t * Cn + cp0) = onehot4(tag, cp0);
      }
    }
    return;
  }

  int tag = 0;
  if (wv == 0) {
    // last_tag + one-hot row T-1 (while helpers preload chunk 0)
    float4 a = *(const float4*)(sb + (size_t)(Tn - 1) * Cn + cp0);
    float v = a.x; int i = cp0; bool cnd;
    cnd = a.y > v; v = cnd ? a.y : v; i = cnd ? cp0 + 1 : i;
    cnd = a.z > v; v = cnd ? a.z : v; i = cnd ? cp0 + 2 : i;
    cnd = a.w > v; v = cnd ? a.w : v; i = cnd ? cp0 + 3 : i;
    tag = argmax64_fast(v, i);
    *(float4*)(ob + (size_t)(Tn - 1) * Cn + cp0) = onehot4(tag, cp0);
  } else if (wv <= 2) {
    // preload chunk 0: 15 rows, slot k <-> t = 1022-k
    const int s0 = (wv == 1) ? 0 : 8, s1 = (wv == 1) ? 8 : 15;
    for (int s = s0; s < s1; ++s)
      *(float4*)(&aL[0][s][cp0]) = *(const float4*)(sb + (size_t)(1022 - s) * Cn + cp0);
  }
  __syncthreads();

  // chunk 0: K=15, t0=1022; chunks 1..63: K=16, t0 = 1007-16*(c-1)
  int p = 0, t0 = 1022, K = 15, pt0 = 0, pK = 0;
  for (int ch = 0; ch < 64; ++ch) {
    const int nt0 = t0 - K;
    if (wv == 0) {
      if (ch == 0) tag = chain_chunk<15>(&aL[p][0][0], tagL[p], transT, tag, l);
      else        tag = chain_chunk<16>(&aL[p][0][0], tagL[p], transT, tag, l);
    } else if (wv <= 2) {
      if (ch < 63) {
        const int s0 = (wv == 1) ? 0 : 8, s1 = (wv == 1) ? 8 : 16;
        for (int s = s0; s < s1; ++s)
          *(float4*)(&aL[1 - p][s][cp0]) =
              *(const float4*)(sb + (size_t)(nt0 - s) * Cn + cp0);
      }
    } else {
      if (ch > 0) {
        for (int k = 0; k < pK; ++k)
          *(float4*)(ob + (size_t)(pt0 - k) * Cn + cp0) =
              onehot4(tagL[1 - p][k], cp0);
      }
    }
    __syncthreads();
    pt0 = t0; pK = K; t0 = nt0; K = 16; p ^= 1;
  }
  // final: chunk 63's one-hots (parity 1; rows 15..0)
  if (wv == 3) {
    for (int k = 0; k < 16; ++k)
      *(float4*)(ob + (size_t)(15 - k) * Cn + cp0) = onehot4(tagL[1][k], cp0);
  }
}

extern "C" void kernel_launch(void* const* d_in, const int* in_sizes, int n_in,
                              void* d_out, int out_size, void* d_ws, size_t ws_size,
                              hipStream_t stream) {
  float* seq = (float*)d_in[0];
  const float* trans = (const float*)d_in[1];
  float* out = (float*)d_out;
  float* transT = (float*)d_ws;
  const int useT = (ws_size >= (size_t)Cn * Cn * sizeof(float)) ? 1 : 0;

  crf_fwd_kernel<<<dim3(Bn + 16), dim3(512), 0, stream>>>(seq, trans, transT, useT);
  crf_bwd_kernel<<<dim3(Bn), dim3(256), 0, stream>>>(seq, trans, transT, out, useT);
}

// Round 6
// 1309.172 us; speedup vs baseline: 1.3557x; 1.1067x over previous
//
#include <hip/hip_runtime.h>

#define Bn 64
#define Tn 1024
#define Cn 256

// Raw workgroup barrier that waits ONLY lgkmcnt(0) (LDS writes visible) and
// deliberately leaves global loads/stores in flight across the barrier.
// __syncthreads() would emit s_waitcnt vmcnt(0) lgkmcnt(0) — that vmcnt(0)
// drain of the leader's ~900cy HBM emission load every step is fwd's biggest
// non-VALU cost (R4/R5 analysis). 0xC07F = vmcnt:63 expcnt:7 lgkmcnt:0.
#define FWD_SYNC()                                  \
  do {                                              \
    __builtin_amdgcn_sched_barrier(0);              \
    __builtin_amdgcn_s_waitcnt(0xC07F);             \
    __builtin_amdgcn_s_barrier();                   \
    __builtin_amdgcn_sched_barrier(0);              \
  } while (0)

// ---------------- DPP helpers ----------------
template<int CTRL>
__device__ __forceinline__ float dpp_mov_f(float x) {
  return __int_as_float(__builtin_amdgcn_update_dpp(0, __float_as_int(x), CTRL, 0xF, 0xF, true));
}
template<int CTRL>
__device__ __forceinline__ void max_stage(float& v) {
  const float pv = __int_as_float(__builtin_amdgcn_update_dpp(
      (int)0xFF800000, __float_as_int(v), CTRL, 0xF, 0xF, false));
  v = fmaxf(v, pv);
}

// Fast 64-lane argmax (min index on ties), short dependent chain:
// 6 dpp fmax (value only) -> readlane(max) -> ballot(v==max) -> ff1 -> readlane(i).
// Tie-break: first set lane = lowest lane = lowest cp block; local i is first
// index within the lane's 4 -> global first index. Matches jnp argmax.
__device__ __forceinline__ int argmax64_fast(float v, int i) {
  float mv = v;
  max_stage<0x111>(mv);  // row_shr:1
  max_stage<0x112>(mv);  // row_shr:2
  max_stage<0x114>(mv);  // row_shr:4
  max_stage<0x118>(mv);  // row_shr:8
  max_stage<0x142>(mv);  // row_bcast15
  max_stage<0x143>(mv);  // row_bcast31  -> lane 63 has global max
  const float smax = __int_as_float(__builtin_amdgcn_readlane(__float_as_int(mv), 63));
  const unsigned long long m = __ballot(v == smax);
  const int ln = __ffsll((unsigned long long)m) - 1;
  return __builtin_amdgcn_readlane(i, ln);
}

// Padded alpha LDS layout (verified R3: SQ_LDS_BANK_CONFLICT 5.0e7 -> 512):
// chunk m at float offset (m>>2)*20 + (m&3)*4.
__device__ __forceinline__ int apad(int m) { return (m >> 2) * 20 + (m & 3) * 4; }

// ---------------- Kernel A: forward max-plus scan (+ trans transpose) ----------------
// R3 16-wave structure (best measured fwd: 931us) with FWD_SYNC instead of
// __syncthreads. Blocks 0..63: forward for batch b; alpha_t overwrites
// seq[b][t][:] (harness restores inputs every launch). Blocks 64..79: transpose.
__global__ __launch_bounds__(1024) void crf_fwd_kernel(
    float* __restrict__ seq, const float* __restrict__ trans,
    float* __restrict__ transT, int useT) {
  __shared__ float lds[64 * 65];
  const int bi = blockIdx.x;
  const int tid = threadIdx.x;

  if (bi < Bn) {
    float* sb = seq + (size_t)bi * (Tn * Cn);
    const int l = tid & 63;
    const int w = tid >> 6;     // wave 0..15
    const int c = l & 15;       // cp-chunk within DPP row (reduction index)
    const int g = l >> 4;       // cc-group within wave
    const int ccb = w * 16 + g * 4;  // 4 consecutive cc
    const int cpb = c * 16;          // 16 consecutive cp
    float4 tr4[16];  // trans[cpb+k][ccb..ccb+3] (64 regs; AGPR-sourced is fine)
#pragma unroll
    for (int k = 0; k < 16; ++k)
      tr4[k] = *(const float4*)(trans + (size_t)(cpb + k) * Cn + ccb);

    float* ab0 = lds;        // 320 floats (padded)
    float* ab1 = lds + 320;
    if (tid < 64) *(float4*)(ab0 + apad(tid)) = ((const float4*)sb)[tid];
    const bool leader = (c == 0);
    const int woff = apad(w * 4 + g);
    float4 e4, pna;
    if (leader) e4 = *(const float4*)(sb + Cn + ccb);  // emissions[1]
    FWD_SYNC();

    for (int t = 1; t < Tn; ++t) {
      float4 pf;
      if (leader) {
        if (t > 1) *(float4*)(sb + (size_t)(t - 1) * Cn + ccb) = pna;
        const int tn = (t + 1 < Tn) ? (t + 1) : (Tn - 1);
        pf = *(const float4*)(sb + (size_t)tn * Cn + ccb);
      }
      const float* av = (t & 1) ? ab0 : ab1;
      float* aw = (t & 1) ? ab1 : ab0;
      const float* avc = av + c * 20;
      float m0 = -__builtin_inff(), m1 = m0, m2 = m0, m3 = m0;
#pragma unroll
      for (int j = 0; j < 4; ++j) {
        const float4 a = *(const float4*)(avc + j * 4);
        float4 t0 = tr4[4 * j + 0];
        m0 = fmaxf(m0, a.x + t0.x); m1 = fmaxf(m1, a.x + t0.y);
        m2 = fmaxf(m2, a.x + t0.z); m3 = fmaxf(m3, a.x + t0.w);
        float4 t1 = tr4[4 * j + 1];
        m0 = fmaxf(m0, a.y + t1.x); m1 = fmaxf(m1, a.y + t1.y);
        m2 = fmaxf(m2, a.y + t1.z); m3 = fmaxf(m3, a.y + t1.w);
        float4 t2 = tr4[4 * j + 2];
        m0 = fmaxf(m0, a.z + t2.x); m1 = fmaxf(m1, a.z + t2.y);
        m2 = fmaxf(m2, a.z + t2.z); m3 = fmaxf(m3, a.z + t2.w);
        float4 t3 = tr4[4 * j + 3];
        m0 = fmaxf(m0, a.w + t3.x); m1 = fmaxf(m1, a.w + t3.y);
        m2 = fmaxf(m2, a.w + t3.z); m3 = fmaxf(m3, a.w + t3.w);
      }
      // rotate-reduce max across the 16 c-lanes of this DPP row (exact)
      m0 = fmaxf(m0, dpp_mov_f<0x128>(m0)); m1 = fmaxf(m1, dpp_mov_f<0x128>(m1));
      m2 = fmaxf(m2, dpp_mov_f<0x128>(m2)); m3 = fmaxf(m3, dpp_mov_f<0x128>(m3));
      m0 = fmaxf(m0, dpp_mov_f<0x124>(m0)); m1 = fmaxf(m1, dpp_mov_f<0x124>(m1));
      m2 = fmaxf(m2, dpp_mov_f<0x124>(m2)); m3 = fmaxf(m3, dpp_mov_f<0x124>(m3));
      m0 = fmaxf(m0, dpp_mov_f<0x122>(m0)); m1 = fmaxf(m1, dpp_mov_f<0x122>(m1));
      m2 = fmaxf(m2, dpp_mov_f<0x122>(m2)); m3 = fmaxf(m3, dpp_mov_f<0x122>(m3));
      m0 = fmaxf(m0, dpp_mov_f<0x121>(m0)); m1 = fmaxf(m1, dpp_mov_f<0x121>(m1));
      m2 = fmaxf(m2, dpp_mov_f<0x121>(m2)); m3 = fmaxf(m3, dpp_mov_f<0x121>(m3));
      if (leader) {
        float4 na;
        na.x = m0 + e4.x; na.y = m1 + e4.y; na.z = m2 + e4.z; na.w = m3 + e4.w;
        *(float4*)(aw + woff) = na;
        pna = na;
        e4 = pf;
      }
      FWD_SYNC();
    }
    if (leader) *(float4*)(sb + (size_t)(Tn - 1) * Cn + ccb) = pna;
  } else if (useT) {
    // 64x64-tile transpose of trans into transT, LDS-staged, +1-padded
    const int idx = bi - Bn;  // 0..15
    const int ti = idx >> 2, tj = idx & 3;
    const int tx = tid & 63, ty = tid >> 6;  // ty 0..15
#pragma unroll
    for (int q = 0; q < 4; ++q) {
      const int row = q * 16 + ty;
      lds[tx * 65 + row] = trans[(size_t)(ti * 64 + row) * Cn + tj * 64 + tx];
    }
    __syncthreads();
#pragma unroll
    for (int q = 0; q < 4; ++q) {
      const int row = q * 16 + ty;
      transT[(size_t)(tj * 64 + row) * Cn + ti * 64 + tx] = lds[row * 65 + tx];
    }
  }
}

// ---------------- bwd helpers ----------------
__device__ __forceinline__ float4 onehot4(int tg, int cp0) {
  float4 z;
  z.x = (tg == cp0 + 0) ? 1.0f : 0.0f; z.y = (tg == cp0 + 1) ? 1.0f : 0.0f;
  z.z = (tg == cp0 + 2) ? 1.0f : 0.0f; z.w = (tg == cp0 + 3) ? 1.0f : 0.0f;
  return z;
}

template<int K>
__device__ __forceinline__ int chain_chunk(
    const float* __restrict__ A, int* __restrict__ tags,
    const float* __restrict__ transT, int tag, int l) {
  const int cp0 = l * 4;
#pragma unroll
  for (int k = 0; k < K; ++k) {
    const float4 tv = *(const float4*)(transT + (size_t)tag * Cn + cp0);
    const float4 ac = *(const float4*)(A + k * Cn + cp0);
    float v = ac.x + tv.x; int i = cp0;
    float vv; bool cnd;
    vv = ac.y + tv.y; cnd = vv > v; v = cnd ? vv : v; i = cnd ? cp0 + 1 : i;
    vv = ac.z + tv.z; cnd = vv > v; v = cnd ? vv : v; i = cnd ? cp0 + 2 : i;
    vv = ac.w + tv.w; cnd = vv > v; v = cnd ? vv : v; i = cnd ? cp0 + 3 : i;
    tag = argmax64_fast(v, i);
    if (l == 0) tags[k] = tag;
  }
  return tag;
}

// ---------------- Kernel B: producer-consumer backtrack + one-hot -------------
// (R5 structure, verified ~358us.) Wave0: pure dependent chain (only vmem op =
// transT[tag], L2). Waves1-2: prefetch next chunk's alpha rows global->LDS ring.
// Wave3: store previous chunk's one-hot rows. Barrier once per 16 steps.
__global__ __launch_bounds__(256) void crf_bwd_kernel(
    const float* __restrict__ seq, const float* __restrict__ trans,
    const float* __restrict__ transT, float* __restrict__ out, int useT) {
  __shared__ float aL[2][16][Cn];   // 32 KB alpha ring
  __shared__ int tagL[2][16];
  const int b = blockIdx.x;
  const int tid = threadIdx.x;
  const int wv = tid >> 6;
  const int l = tid & 63;
  const int cp0 = l * 4;
  const float* sb = seq + (size_t)b * (Tn * Cn);  // alpha trail
  float* ob = out + (size_t)b * (Tn * Cn);

  if (!useT) {
    if (wv == 0) {
      float4 a = *(const float4*)(sb + (size_t)(Tn - 1) * Cn + cp0);
      float v = a.x; int i = cp0; bool cnd;
      cnd = a.y > v; v = cnd ? a.y : v; i = cnd ? cp0 + 1 : i;
      cnd = a.z > v; v = cnd ? a.z : v; i = cnd ? cp0 + 2 : i;
      cnd = a.w > v; v = cnd ? a.w : v; i = cnd ? cp0 + 3 : i;
      int tag = argmax64_fast(v, i);
      *(float4*)(ob + (size_t)(Tn - 1) * Cn + cp0) = onehot4(tag, cp0);
      for (int t = Tn - 2; t >= 0; --t) {
        const float4 ac = *(const float4*)(sb + (size_t)t * Cn + cp0);
        float4 tv;
        tv.x = trans[(size_t)(cp0 + 0) * Cn + tag];
        tv.y = trans[(size_t)(cp0 + 1) * Cn + tag];
        tv.z = trans[(size_t)(cp0 + 2) * Cn + tag];
        tv.w = trans[(size_t)(cp0 + 3) * Cn + tag];
        float v2 = ac.x + tv.x; int i2 = cp0; float vv; bool c2;
        vv = ac.y + tv.y; c2 = vv > v2; v2 = c2 ? vv : v2; i2 = c2 ? cp0 + 1 : i2;
        vv = ac.z + tv.z; c2 = vv > v2; v2 = c2 ? vv : v2; i2 = c2 ? cp0 + 2 : i2;
        vv = ac.w + tv.w; c2 = vv > v2; v2 = c2 ? vv : v2; i2 = c2 ? cp0 + 3 : i2;
        tag = argmax64_fast(v2, i2);
        *(float4*)(ob + (size_t)t * Cn + cp0) = onehot4(tag, cp0);
      }
    }
    return;
  }

  int tag = 0;
  if (wv == 0) {
    float4 a = *(const float4*)(sb + (size_t)(Tn - 1) * Cn + cp0);
    float v = a.x; int i = cp0; bool cnd;
    cnd = a.y > v; v = cnd ? a.y : v; i = cnd ? cp0 + 1 : i;
    cnd = a.z > v; v = cnd ? a.z : v; i = cnd ? cp0 + 2 : i;
    cnd = a.w > v; v = cnd ? a.w : v; i = cnd ? cp0 + 3 : i;
    tag = argmax64_fast(v, i);
    *(float4*)(ob + (size_t)(Tn - 1) * Cn + cp0) = onehot4(tag, cp0);
  } else if (wv <= 2) {
    // preload chunk 0: 15 rows, slot k <-> t = 1022-k
    const int s0 = (wv == 1) ? 0 : 8, s1 = (wv == 1) ? 8 : 15;
    for (int s = s0; s < s1; ++s)
      *(float4*)(&aL[0][s][cp0]) = *(const float4*)(sb + (size_t)(1022 - s) * Cn + cp0);
  }
  __syncthreads();

  int p = 0, t0 = 1022, K = 15, pt0 = 0, pK = 0;
  for (int ch = 0; ch < 64; ++ch) {
    const int nt0 = t0 - K;
    if (wv == 0) {
      if (ch == 0) tag = chain_chunk<15>(&aL[p][0][0], tagL[p], transT, tag, l);
      else        tag = chain_chunk<16>(&aL[p][0][0], tagL[p], transT, tag, l);
    } else if (wv <= 2) {
      if (ch < 63) {
        const int s0 = (wv == 1) ? 0 : 8, s1 = (wv == 1) ? 8 : 16;
        for (int s = s0; s < s1; ++s)
          *(float4*)(&aL[1 - p][s][cp0]) =
              *(const float4*)(sb + (size_t)(nt0 - s) * Cn + cp0);
      }
    } else {
      if (ch > 0) {
        for (int k = 0; k < pK; ++k)
          *(float4*)(ob + (size_t)(pt0 - k) * Cn + cp0) =
              onehot4(tagL[1 - p][k], cp0);
      }
    }
    __syncthreads();
    pt0 = t0; pK = K; t0 = nt0; K = 16; p ^= 1;
  }
  if (wv == 3) {
    for (int k = 0; k < 16; ++k)
      *(float4*)(ob + (size_t)(15 - k) * Cn + cp0) = onehot4(tagL[1][k], cp0);
  }
}

extern "C" void kernel_launch(void* const* d_in, const int* in_sizes, int n_in,
                              void* d_out, int out_size, void* d_ws, size_t ws_size,
                              hipStream_t stream) {
  float* seq = (float*)d_in[0];
  const float* trans = (const float*)d_in[1];
  float* out = (float*)d_out;
  float* transT = (float*)d_ws;
  const int useT = (ws_size >= (size_t)Cn * Cn * sizeof(float)) ? 1 : 0;

  crf_fwd_kernel<<<dim3(Bn + 16), dim3(1024), 0, stream>>>(seq, trans, transT, useT);
  crf_bwd_kernel<<<dim3(Bn), dim3(256), 0, stream>>>(seq, trans, transT, out, useT);
}